// Round 5
// baseline (135.868 us; speedup 1.0000x reference)
//
#include <hip/hip_runtime.h>
#include <hip/hip_bf16.h>
#include <hip/hip_fp16.h>

// SpMM: out[r] = sum_e (rows[e]==r) vals[e] * x[cols[e], :]
// rows sorted ascending (CSR-like). N=100000, E=1600000, D=48.
//
// R3 findings: fp16 gather works (absmax 0.0625 << 0.3). ~80us of total is
// harness ws-poison fills (268 MB @ 6 TB/s) we can't control. Remaining
// levers are cache-line economics of the random gather:
//  - pad fp16 rows to 128 B stride -> every row gather is exactly ONE
//    aligned L2 line (was avg 1.5 lines at stride 96).
//  - nontemporal loads for the cols/vals edge stream and nontemporal
//    stores for out -> stop 31 MB of single-use stream from evicting x
//    out of the 4 MB per-XCD L2.
// R4 fix: __builtin_nontemporal_* requires native clang vectors, not
// HIP_vector_type classes -> use ext_vector_type typedefs.

#define D_FEAT 48
#define XH_STRIDE 64    // halfs per row in the fp16 copy (128 B, line-aligned)
#define TPR 12          // threads per row (each owns a 4-feature slice)
#define RPB 16          // rows per block
#define BLOCK (TPR * RPB)  // 192

typedef float  vfloat4  __attribute__((ext_vector_type(4)));
typedef unsigned short vushort4 __attribute__((ext_vector_type(4)));

__global__ void build_row_ptr_scatter(const int* __restrict__ rows,
                                      int* __restrict__ row_ptr,
                                      int n_edges, int n_nodes) {
    int e = blockIdx.x * blockDim.x + threadIdx.x;
    if (e >= n_edges) return;
    const int r     = rows[e];
    const int rprev = (e == 0) ? -1 : rows[e - 1];
    for (int q = rprev + 1; q <= r; ++q) row_ptr[q] = e;
    if (e == n_edges - 1) {
        for (int q = r + 1; q <= n_nodes; ++q) row_ptr[q] = n_edges;
    }
}

// One thread per 4 source floats -> one 8 B fp16 write into the padded row.
__global__ void convert_x_f16(const float* __restrict__ x,
                              __half* __restrict__ xh, int n4) {
    int i = blockIdx.x * blockDim.x + threadIdx.x;
    if (i >= n4) return;
    const vfloat4 f = __builtin_nontemporal_load(
        reinterpret_cast<const vfloat4*>(x) + i);
    union { vushort4 u; __half2 h2[2]; } pk;
    pk.h2[0] = __floats2half2_rn(f.x, f.y);
    pk.h2[1] = __floats2half2_rn(f.z, f.w);
    const int node = i / TPR;          // 12 groups of 4 floats per row
    const int fg   = i % TPR;
    __builtin_nontemporal_store(pk.u,
        reinterpret_cast<vushort4*>(xh + (size_t)node * XH_STRIDE + fg * 4));
}

__device__ __forceinline__ void fma4_h(vfloat4& acc, float v, const __half* p) {
    union { vushort4 u; __half2 h2[2]; } w;
    w.u = *reinterpret_cast<const vushort4*>(p);      // 8 B cached load (x reuse)
    const float2 f0 = __half22float2(w.h2[0]);
    const float2 f1 = __half22float2(w.h2[1]);
    acc.x += v * f0.x;
    acc.y += v * f0.y;
    acc.z += v * f1.x;
    acc.w += v * f1.y;
}

__global__ __launch_bounds__(BLOCK) void spmm_rows_f16(
        const int* __restrict__ row_ptr,
        const int* __restrict__ cols,
        const float* __restrict__ vals,
        const __half* __restrict__ xh,
        float* __restrict__ out,
        int n_nodes) {
    const int tid = threadIdx.x;
    const int fg  = tid % TPR;
    const int rib = tid / TPR;
    const int r   = blockIdx.x * RPB + rib;
    if (r >= n_nodes) return;

    const int e0 = row_ptr[r];
    const int e1 = row_ptr[r + 1];

    vfloat4 acc = (vfloat4)(0.f);

    int e = e0;
    for (; e + 3 < e1; e += 4) {
        const int   c0 = __builtin_nontemporal_load(cols + e);
        const int   c1 = __builtin_nontemporal_load(cols + e + 1);
        const int   c2 = __builtin_nontemporal_load(cols + e + 2);
        const int   c3 = __builtin_nontemporal_load(cols + e + 3);
        const float v0 = __builtin_nontemporal_load(vals + e);
        const float v1 = __builtin_nontemporal_load(vals + e + 1);
        const float v2 = __builtin_nontemporal_load(vals + e + 2);
        const float v3 = __builtin_nontemporal_load(vals + e + 3);
        fma4_h(acc, v0, xh + (size_t)c0 * XH_STRIDE + fg * 4);
        fma4_h(acc, v1, xh + (size_t)c1 * XH_STRIDE + fg * 4);
        fma4_h(acc, v2, xh + (size_t)c2 * XH_STRIDE + fg * 4);
        fma4_h(acc, v3, xh + (size_t)c3 * XH_STRIDE + fg * 4);
    }
    for (; e < e1; ++e) {
        const int   c0 = __builtin_nontemporal_load(cols + e);
        const float v0 = __builtin_nontemporal_load(vals + e);
        fma4_h(acc, v0, xh + (size_t)c0 * XH_STRIDE + fg * 4);
    }

    __builtin_nontemporal_store(acc,
        reinterpret_cast<vfloat4*>(out + (size_t)r * D_FEAT + fg * 4));
}

// f32 fallback (used only if ws_size can't hold the fp16 copy)
__global__ __launch_bounds__(BLOCK) void spmm_rows_f32(
        const int* __restrict__ row_ptr,
        const int* __restrict__ cols,
        const float* __restrict__ vals,
        const float* __restrict__ x,
        float* __restrict__ out,
        int n_nodes) {
    const int tid = threadIdx.x;
    const int fg  = tid % TPR;
    const int rib = tid / TPR;
    const int r   = blockIdx.x * RPB + rib;
    if (r >= n_nodes) return;
    const int e0 = row_ptr[r];
    const int e1 = row_ptr[r + 1];
    float4 acc = make_float4(0.f, 0.f, 0.f, 0.f);
    for (int e = e0; e < e1; ++e) {
        const float v = vals[e];
        const float4 xa = *reinterpret_cast<const float4*>(
            x + (size_t)cols[e] * D_FEAT + fg * 4);
        acc.x += v * xa.x; acc.y += v * xa.y;
        acc.z += v * xa.z; acc.w += v * xa.w;
    }
    *reinterpret_cast<float4*>(out + (size_t)r * D_FEAT + fg * 4) = acc;
}

extern "C" void kernel_launch(void* const* d_in, const int* in_sizes, int n_in,
                              void* d_out, int out_size, void* d_ws, size_t ws_size,
                              hipStream_t stream) {
    // inputs: t(f32,1), x(f32,N*48), rows(i32,E), cols(i32,E), vals(f32,E)
    const float* x    = (const float*)d_in[1];
    const int*   rows = (const int*)  d_in[2];
    const int*   cols = (const int*)  d_in[3];
    const float* vals = (const float*)d_in[4];
    float*       out  = (float*)d_out;

    const int n_edges = in_sizes[2];
    const int n_x     = in_sizes[1];           // n_nodes * 48
    const int n_nodes = out_size / D_FEAT;     // 100000

    int* row_ptr = (int*)d_ws;                 // (n_nodes+1) ints
    const size_t rp_bytes  = (size_t)(n_nodes + 1) * sizeof(int);
    const size_t xh_off    = (rp_bytes + 255) & ~(size_t)255;
    const size_t need      = xh_off + (size_t)n_nodes * XH_STRIDE * sizeof(__half);

    {
        const int threads = 256;
        const int grid = (n_edges + threads - 1) / threads;
        build_row_ptr_scatter<<<grid, threads, 0, stream>>>(rows, row_ptr, n_edges, n_nodes);
    }

    if (ws_size >= need) {
        __half* xh = (__half*)((char*)d_ws + xh_off);
        {
            const int n4 = n_x / 4;
            const int threads = 256;
            const int grid = (n4 + threads - 1) / threads;
            convert_x_f16<<<grid, threads, 0, stream>>>(x, xh, n4);
        }
        const int grid = (n_nodes + RPB - 1) / RPB;
        spmm_rows_f16<<<grid, BLOCK, 0, stream>>>(row_ptr, cols, vals, xh, out, n_nodes);
    } else {
        const int grid = (n_nodes + RPB - 1) / RPB;
        spmm_rows_f32<<<grid, BLOCK, 0, stream>>>(row_ptr, cols, vals, x, out, n_nodes);
    }
}

// Round 6
// 127.381 us; speedup vs baseline: 1.0666x; 1.0666x over previous
//
#include <hip/hip_runtime.h>
#include <hip/hip_bf16.h>
#include <hip/hip_fp16.h>

// SpMM: out[r] = sum_e (rows[e]==r) vals[e] * x[cols[e], :]
// rows sorted ascending (CSR-like). N=100000, E=1600000, D=48.
//
// R5 post-mortem: L2 fetches 64 B sectors -> unpadded 96 B fp16 rows already
// cost 128 B/miss; padding to 128 B only inflated footprint (9.6->12.8 MB)
// and cut hit rate. nt on cols/vals killed intra-block edge-line reuse.
// R6: revert to stride-48 fp16 + cached edge loads; nt ONLY on the out
// store (write-once stream); 8-deep edge unroll for gather MLP.

#define D_FEAT 48
#define TPR 12          // threads per row (each owns a 4-feature slice)
#define RPB 16          // rows per block
#define BLOCK (TPR * RPB)  // 192

typedef float vfloat4 __attribute__((ext_vector_type(4)));

__global__ void build_row_ptr_scatter(const int* __restrict__ rows,
                                      int* __restrict__ row_ptr,
                                      int n_edges, int n_nodes) {
    int e = blockIdx.x * blockDim.x + threadIdx.x;
    if (e >= n_edges) return;
    const int r     = rows[e];
    const int rprev = (e == 0) ? -1 : rows[e - 1];
    for (int q = rprev + 1; q <= r; ++q) row_ptr[q] = e;
    if (e == n_edges - 1) {
        for (int q = r + 1; q <= n_nodes; ++q) row_ptr[q] = n_edges;
    }
}

// One thread per 4 source floats -> one 8 B fp16 write (dense stride 48).
__global__ void convert_x_f16(const float* __restrict__ x,
                              __half* __restrict__ xh, int n4) {
    int i = blockIdx.x * blockDim.x + threadIdx.x;
    if (i >= n4) return;
    const float4 f = reinterpret_cast<const float4*>(x)[i];
    union { ushort4 u; __half2 h2[2]; } pk;
    pk.h2[0] = __floats2half2_rn(f.x, f.y);
    pk.h2[1] = __floats2half2_rn(f.z, f.w);
    reinterpret_cast<ushort4*>(xh)[i] = pk.u;
}

__device__ __forceinline__ void fma4_h(vfloat4& acc, float v, const __half* p) {
    union { ushort4 u; __half2 h2[2]; } w;
    w.u = *reinterpret_cast<const ushort4*>(p);       // 8 B cached load (x reuse)
    const float2 f0 = __half22float2(w.h2[0]);
    const float2 f1 = __half22float2(w.h2[1]);
    acc.x += v * f0.x;
    acc.y += v * f0.y;
    acc.z += v * f1.x;
    acc.w += v * f1.y;
}

__global__ __launch_bounds__(BLOCK) void spmm_rows_f16(
        const int* __restrict__ row_ptr,
        const int* __restrict__ cols,
        const float* __restrict__ vals,
        const __half* __restrict__ xh,
        float* __restrict__ out,
        int n_nodes) {
    const int tid = threadIdx.x;
    const int fg  = tid % TPR;
    const int rib = tid / TPR;
    const int r   = blockIdx.x * RPB + rib;
    if (r >= n_nodes) return;

    const int e0 = row_ptr[r];
    const int e1 = row_ptr[r + 1];

    vfloat4 acc = (vfloat4)(0.f);

    int e = e0;
    // 8-edge unroll: eight independent gather chains in flight per thread.
    for (; e + 7 < e1; e += 8) {
        int   c[8];
        float v[8];
#pragma unroll
        for (int j = 0; j < 8; ++j) { c[j] = cols[e + j]; v[j] = vals[e + j]; }
#pragma unroll
        for (int j = 0; j < 8; ++j)
            fma4_h(acc, v[j], xh + (size_t)c[j] * D_FEAT + fg * 4);
    }
    for (; e + 3 < e1; e += 4) {
        int   c[4];
        float v[4];
#pragma unroll
        for (int j = 0; j < 4; ++j) { c[j] = cols[e + j]; v[j] = vals[e + j]; }
#pragma unroll
        for (int j = 0; j < 4; ++j)
            fma4_h(acc, v[j], xh + (size_t)c[j] * D_FEAT + fg * 4);
    }
    for (; e < e1; ++e) {
        fma4_h(acc, vals[e], xh + (size_t)cols[e] * D_FEAT + fg * 4);
    }

    __builtin_nontemporal_store(acc,
        reinterpret_cast<vfloat4*>(out + (size_t)r * D_FEAT + fg * 4));
}

// f32 fallback (used only if ws_size can't hold the fp16 copy)
__global__ __launch_bounds__(BLOCK) void spmm_rows_f32(
        const int* __restrict__ row_ptr,
        const int* __restrict__ cols,
        const float* __restrict__ vals,
        const float* __restrict__ x,
        float* __restrict__ out,
        int n_nodes) {
    const int tid = threadIdx.x;
    const int fg  = tid % TPR;
    const int rib = tid / TPR;
    const int r   = blockIdx.x * RPB + rib;
    if (r >= n_nodes) return;
    const int e0 = row_ptr[r];
    const int e1 = row_ptr[r + 1];
    float4 acc = make_float4(0.f, 0.f, 0.f, 0.f);
    for (int e = e0; e < e1; ++e) {
        const float v = vals[e];
        const float4 xa = *reinterpret_cast<const float4*>(
            x + (size_t)cols[e] * D_FEAT + fg * 4);
        acc.x += v * xa.x; acc.y += v * xa.y;
        acc.z += v * xa.z; acc.w += v * xa.w;
    }
    *reinterpret_cast<float4*>(out + (size_t)r * D_FEAT + fg * 4) = acc;
}

extern "C" void kernel_launch(void* const* d_in, const int* in_sizes, int n_in,
                              void* d_out, int out_size, void* d_ws, size_t ws_size,
                              hipStream_t stream) {
    // inputs: t(f32,1), x(f32,N*48), rows(i32,E), cols(i32,E), vals(f32,E)
    const float* x    = (const float*)d_in[1];
    const int*   rows = (const int*)  d_in[2];
    const int*   cols = (const int*)  d_in[3];
    const float* vals = (const float*)d_in[4];
    float*       out  = (float*)d_out;

    const int n_edges = in_sizes[2];
    const int n_x     = in_sizes[1];           // n_nodes * 48
    const int n_nodes = out_size / D_FEAT;     // 100000

    int* row_ptr = (int*)d_ws;                 // (n_nodes+1) ints
    const size_t rp_bytes  = (size_t)(n_nodes + 1) * sizeof(int);
    const size_t xh_off    = (rp_bytes + 255) & ~(size_t)255;
    const size_t need      = xh_off + (size_t)n_x * sizeof(__half);

    {
        const int threads = 256;
        const int grid = (n_edges + threads - 1) / threads;
        build_row_ptr_scatter<<<grid, threads, 0, stream>>>(rows, row_ptr, n_edges, n_nodes);
    }

    if (ws_size >= need) {
        __half* xh = (__half*)((char*)d_ws + xh_off);
        {
            const int n4 = n_x / 4;
            const int threads = 256;
            const int grid = (n4 + threads - 1) / threads;
            convert_x_f16<<<grid, threads, 0, stream>>>(x, xh, n4);
        }
        const int grid = (n_nodes + RPB - 1) / RPB;
        spmm_rows_f16<<<grid, BLOCK, 0, stream>>>(row_ptr, cols, vals, xh, out, n_nodes);
    } else {
        const int grid = (n_nodes + RPB - 1) / RPB;
        spmm_rows_f32<<<grid, BLOCK, 0, stream>>>(row_ptr, cols, vals, x, out, n_nodes);
    }
}